// Round 1
// baseline (363.693 us; speedup 1.0000x reference)
//
#include <hip/hip_runtime.h>
#include <hip/hip_bf16.h>

// Problem constants: B=8 L=8192 C=384 DIN=128 HID=512, tokens = 65536.
// Key identity: softmax over a size-1 axis == 1, so attention out == v.
// z = y + gelu(LN2(y)@W1+bm1)@W2 + bm2,  y = LN1(x)@Wc + bc,
//   Wc = Wkv[:,128:256]@Wp (folded),  bc = bkv[128:]@Wp + bp.

typedef __attribute__((ext_vector_type(8))) short bf16x8;
typedef __attribute__((ext_vector_type(4))) float f32x4;

__device__ __forceinline__ short f2bf(float f) {
  union { float f; unsigned u; } a; a.f = f;
  unsigned u = a.u;
  u += 0x7fffu + ((u >> 16) & 1u);   // RNE; inputs are finite
  return (short)(u >> 16);
}

// ---------------- prologue: fold Wc = Wv@Wp, transpose W1/W2 to [n][k] bf16 ----
__global__ void prep_kernel(const float* __restrict__ Wkv, const float* __restrict__ bkv,
                            const float* __restrict__ Wp,  const float* __restrict__ bp,
                            const float* __restrict__ W1,  const float* __restrict__ W2,
                            short* __restrict__ WcT, short* __restrict__ W1T,
                            short* __restrict__ W2T, float* __restrict__ bc) {
  int id = blockIdx.x * 256 + threadIdx.x;
  if (id < 49152) {                       // WcT[n][k], n<128, k<384
    int n = id / 384, k = id % 384;
    float s = 0.f;
    for (int m = 0; m < 128; ++m)
      s += Wkv[k * 256 + 128 + m] * Wp[m * 128 + n];
    WcT[n * 384 + k] = f2bf(s);
  } else if (id < 49280) {                // bc[n]
    int n = id - 49152;
    float s = bp[n];
    for (int m = 0; m < 128; ++m)
      s += bkv[128 + m] * Wp[m * 128 + n];
    bc[n] = s;
  } else if (id < 49280 + 65536) {        // W1T[n][k] = W1[k][n], n<512, k<128
    int e = id - 49280;
    int n = e >> 7, k = e & 127;
    W1T[n * 128 + k] = f2bf(W1[k * 512 + n]);
  } else if (id < 49280 + 131072) {       // W2T[n][k] = W2[k][n], n<128, k<512
    int e = id - 49280 - 65536;
    int n = e >> 9, k = e & 511;
    W2T[n * 512 + k] = f2bf(W2[k * 128 + n]);
  }
}

// ---------------- fused main: 64-token tile per block, 4 waves ----------------
// LDS: params 4096 B | union region: A1 [64][392]bf16 (50176 B)  aliased by
//                      A2 [64][136]bf16 (17408 B) + A3 [64][72]bf16 (9216 B)
// All A-buffers are written & read within a wave's own 16-row band → no
// barriers except: (1) after param staging + S1, (2) before A2 writes (A1 alias).
__global__ __launch_bounds__(256, 3)
void fused_main(const float* __restrict__ x,  const float* __restrict__ g1,
                const float* __restrict__ b1, const float* __restrict__ g2,
                const float* __restrict__ b2, const float* __restrict__ bm1,
                const float* __restrict__ bm2,
                const short* __restrict__ WcT, const short* __restrict__ W1T,
                const short* __restrict__ W2T, const float* __restrict__ bcp,
                float* __restrict__ out) {
  __shared__ __align__(16) char smem[54272];
  float* bm1f = (float*)smem;             // 512 f
  float* bcf  = (float*)(smem + 2048);    // 128 f
  float* g2f  = (float*)(smem + 2560);    // 128 f
  float* b2f  = (float*)(smem + 3072);    // 128 f
  float* bm2f = (float*)(smem + 3584);    // 128 f
  short* A1 = (short*)(smem + 4096);      // [64][392]
  short* A2 = (short*)(smem + 4096);      // [64][136] (aliases A1)
  short* A3 = (short*)(smem + 4096 + 17408); // [64][72]

  const int tid  = threadIdx.x;
  const int lane = tid & 63;
  const int w    = tid >> 6;
  const long tok0 = (long)blockIdx.x * 64;

  // param staging (reads cross-wave later -> covered by barrier below)
  if (tid < 128)      ((float4*)bm1f)[tid]       = ((const float4*)bm1)[tid];
  else if (tid < 160) ((float4*)bcf)[tid - 128]  = ((const float4*)bcp)[tid - 128];
  else if (tid < 192) ((float4*)g2f)[tid - 160]  = ((const float4*)g2)[tid - 160];
  else if (tid < 224) ((float4*)b2f)[tid - 192]  = ((const float4*)b2)[tid - 192];
  else                ((float4*)bm2f)[tid - 224] = ((const float4*)bm2)[tid - 224];

  // ---- S1: LN(x) -> A1 (bf16), 4 threads per row, 96 elems each ----
  {
    const int row  = tid >> 2;
    const int part = tid & 3;
    const float* xp = x + (tok0 + row) * 384 + part * 96;
    float4 xv[24];
    float s = 0.f, sq = 0.f;
#pragma unroll
    for (int i = 0; i < 24; ++i) {
      float4 v = ((const float4*)xp)[i];
      xv[i] = v;
      s  += v.x + v.y + v.z + v.w;
      sq += v.x * v.x + v.y * v.y + v.z * v.z + v.w * v.w;
    }
    s  += __shfl_xor(s, 1);  s  += __shfl_xor(s, 2);
    sq += __shfl_xor(sq, 1); sq += __shfl_xor(sq, 2);
    const float mean = s * (1.f / 384.f);
    const float var  = sq * (1.f / 384.f) - mean * mean;
    const float rs   = rsqrtf(var + 1e-5f);
    const float4* g1p = (const float4*)(g1 + part * 96);
    const float4* b1p = (const float4*)(b1 + part * 96);
    short* dst = A1 + row * 392 + part * 96;
#pragma unroll
    for (int i = 0; i < 24; ++i) {
      float4 g = g1p[i], b = b1p[i], v = xv[i];
      short4 o;
      o.x = f2bf((v.x - mean) * rs * g.x + b.x);
      o.y = f2bf((v.y - mean) * rs * g.y + b.y);
      o.z = f2bf((v.z - mean) * rs * g.z + b.z);
      o.w = f2bf((v.w - mean) * rs * g.w + b.w);
      ((short4*)dst)[i] = o;
    }
  }
  __syncthreads();

  // ---- S2: y[64][128] = A1 @ Wc + bc (MFMA 16x16x32, wave = 16 rows x 128 cols)
  const int q    = lane >> 4;
  const int c16  = lane & 15;
  const int arow = w * 16 + c16;
  const f32x4 zero4 = {0.f, 0.f, 0.f, 0.f};
  f32x4 yacc[8];
#pragma unroll
  for (int t = 0; t < 8; ++t) yacc[t] = zero4;
#pragma unroll
  for (int ks = 0; ks < 12; ++ks) {
    bf16x8 af = *(const bf16x8*)(A1 + arow * 392 + ks * 32 + q * 8);
#pragma unroll
    for (int t = 0; t < 8; ++t) {
      bf16x8 bf = *(const bf16x8*)(WcT + (t * 16 + c16) * 384 + ks * 32 + q * 8);
      yacc[t] = __builtin_amdgcn_mfma_f32_16x16x32_bf16(af, bf, yacc[t], 0, 0, 0);
    }
  }
#pragma unroll
  for (int t = 0; t < 8; ++t) {
    float bb = bcf[t * 16 + c16];
#pragma unroll
    for (int r = 0; r < 4; ++r) yacc[t][r] += bb;
  }

  // ---- S3: LN(y) over 128 cols; row sums live across the 16-lane group ----
  float sm[4] = {0, 0, 0, 0}, sv[4] = {0, 0, 0, 0};
#pragma unroll
  for (int t = 0; t < 8; ++t)
#pragma unroll
    for (int r = 0; r < 4; ++r) { float v = yacc[t][r]; sm[r] += v; sv[r] += v * v; }
#pragma unroll
  for (int r = 0; r < 4; ++r) {
    sm[r] += __shfl_xor(sm[r], 1); sm[r] += __shfl_xor(sm[r], 2);
    sm[r] += __shfl_xor(sm[r], 4); sm[r] += __shfl_xor(sm[r], 8);
    sv[r] += __shfl_xor(sv[r], 1); sv[r] += __shfl_xor(sv[r], 2);
    sv[r] += __shfl_xor(sv[r], 4); sv[r] += __shfl_xor(sv[r], 8);
  }
  float mn[4], rv[4];
#pragma unroll
  for (int r = 0; r < 4; ++r) {
    mn[r] = sm[r] * (1.f / 128.f);
    float var = sv[r] * (1.f / 128.f) - mn[r] * mn[r];
    rv[r] = rsqrtf(var + 1e-5f);
  }
  __syncthreads();   // A2 aliases A1: all waves must be done reading A1
#pragma unroll
  for (int t = 0; t < 8; ++t) {
    const int col = t * 16 + c16;
    const float g = g2f[col], bb = b2f[col];
#pragma unroll
    for (int r = 0; r < 4; ++r) {
      A2[(w * 16 + q * 4 + r) * 136 + col] = f2bf((yacc[t][r] - mn[r]) * rv[r] * g + bb);
    }
  }

  // ---- S4+S5: MLP in N-chunks of 64: h1 = gelu(A2@W1+bm1) -> A3 -> z += A3@W2
  f32x4 zacc[8];
#pragma unroll
  for (int t = 0; t < 8; ++t) zacc[t] = zero4;

  for (int ch = 0; ch < 8; ++ch) {
    f32x4 hacc[4];
#pragma unroll
    for (int tt = 0; tt < 4; ++tt) hacc[tt] = zero4;
#pragma unroll
    for (int ks = 0; ks < 4; ++ks) {
      bf16x8 af = *(const bf16x8*)(A2 + arow * 136 + ks * 32 + q * 8);
#pragma unroll
      for (int tt = 0; tt < 4; ++tt) {
        bf16x8 bf = *(const bf16x8*)(W1T + (ch * 64 + tt * 16 + c16) * 128 + ks * 32 + q * 8);
        hacc[tt] = __builtin_amdgcn_mfma_f32_16x16x32_bf16(af, bf, hacc[tt], 0, 0, 0);
      }
    }
#pragma unroll
    for (int tt = 0; tt < 4; ++tt) {
      const float bb = bm1f[ch * 64 + tt * 16 + c16];
#pragma unroll
      for (int r = 0; r < 4; ++r) {
        float h  = hacc[tt][r] + bb;
        float ge = 0.5f * h * (1.f + erff(h * 0.70710678118f));  // exact gelu
        A3[(w * 16 + q * 4 + r) * 72 + tt * 16 + c16] = f2bf(ge);
      }
    }
#pragma unroll
    for (int ks = 0; ks < 2; ++ks) {
      bf16x8 af = *(const bf16x8*)(A3 + arow * 72 + ks * 32 + q * 8);
#pragma unroll
      for (int t = 0; t < 8; ++t) {
        bf16x8 bf = *(const bf16x8*)(W2T + (t * 16 + c16) * 512 + ch * 64 + ks * 32 + q * 8);
        zacc[t] = __builtin_amdgcn_mfma_f32_16x16x32_bf16(af, bf, zacc[t], 0, 0, 0);
      }
    }
  }

  // ---- epilogue: z = y + mlp + bm2 ----
#pragma unroll
  for (int t = 0; t < 8; ++t) {
    const int col = t * 16 + c16;
    const float bb = bm2f[col];
#pragma unroll
    for (int r = 0; r < 4; ++r) {
      const long rowg = tok0 + w * 16 + q * 4 + r;
      out[rowg * 128 + col] = yacc[t][r] + zacc[t][r] + bb;
    }
  }
}

extern "C" void kernel_launch(void* const* d_in, const int* in_sizes, int n_in,
                              void* d_out, int out_size, void* d_ws, size_t ws_size,
                              hipStream_t stream) {
  const float* x   = (const float*)d_in[0];
  const float* g1  = (const float*)d_in[1];
  const float* b1  = (const float*)d_in[2];
  // d_in[3]=Wq, d_in[4]=bq, d_in[7]=rpb: dead (softmax over size-1 axis == 1)
  const float* Wkv = (const float*)d_in[5];
  const float* bkv = (const float*)d_in[6];
  const float* Wp  = (const float*)d_in[8];
  const float* bp  = (const float*)d_in[9];
  const float* g2  = (const float*)d_in[10];
  const float* b2  = (const float*)d_in[11];
  const float* W1  = (const float*)d_in[12];
  const float* bm1 = (const float*)d_in[13];
  const float* W2  = (const float*)d_in[14];
  const float* bm2 = (const float*)d_in[15];

  short* WcT = (short*)d_ws;                         // 128*384 bf16 = 98304 B
  short* W1T = (short*)((char*)d_ws + 98304);        // 512*128 bf16 = 131072 B
  short* W2T = (short*)((char*)d_ws + 229376);       // 128*512 bf16 = 131072 B
  float* bc  = (float*)((char*)d_ws + 360448);       // 128 f32

  prep_kernel<<<705, 256, 0, stream>>>(Wkv, bkv, Wp, bp, W1, W2, WcT, W1T, W2T, bc);
  fused_main<<<1024, 256, 0, stream>>>(x, g1, b1, g2, b2, bm1, bm2,
                                       WcT, W1T, W2T, bc, (float*)d_out);
}

// Round 2
// 264.841 us; speedup vs baseline: 1.3733x; 1.3733x over previous
//
#include <hip/hip_runtime.h>
#include <hip/hip_bf16.h>
#include <stdint.h>

// B=8 L=8192 C=384 DIN=128 HID=512, tokens=65536.
// softmax over size-1 axis == 1 -> attention out == v -> fold Wc = Wv@Wp.
// z = y + gelu(LN2(y)@W1+bm1)@W2 + bm2,  y = LN1(x)@Wc + bc.
// R2: weights via LDS (global_load_lds w=16), two streaming kernels,
// frag-major bf16 intermediates (y, ln2y) in d_ws.

typedef __attribute__((ext_vector_type(8))) short bf16x8;
typedef __attribute__((ext_vector_type(4))) float f32x4;

__device__ __forceinline__ short f2bf(float f) {
  union { float f; unsigned u; } a; a.f = f;
  unsigned u = a.u;
  u += 0x7fffu + ((u >> 16) & 1u);   // RNE, finite inputs
  return (short)(u >> 16);
}
__device__ __forceinline__ float bf2f(short s) {
  union { unsigned u; float f; } a; a.u = ((unsigned)(unsigned short)s) << 16;
  return a.f;
}
__device__ __forceinline__ void gload_lds16(const void* g, void* l) {
  // async global->LDS, 16B/lane; LDS dest = wave-uniform base + lane*16
  __builtin_amdgcn_global_load_lds(
      (const __attribute__((address_space(1))) unsigned*)g,
      (__attribute__((address_space(3))) unsigned*)l, 16, 0, 0);
}

// ---------------- prep: fold WcT[n][392], transpose W1T[512][136], W2T chunked,
// bc. Layouts padded so each is a multiple of 1024 B for global_load_lds staging.
__global__ void prep(const float* __restrict__ Wkv, const float* __restrict__ bkv,
                     const float* __restrict__ Wp,  const float* __restrict__ bp,
                     const float* __restrict__ W1,  const float* __restrict__ W2,
                     short* __restrict__ WcT, short* __restrict__ W1T,
                     short* __restrict__ W2T, float* __restrict__ bc) {
  const int b = blockIdx.x, tid = threadIdx.x;
  if (b < 192) {                       // WcT fold: k = 2b + (tid>>7), n = tid&127
    __shared__ float wv[2][128];
    const int kk = tid >> 7, n = tid & 127;
    wv[kk][n] = Wkv[(2 * b + kk) * 256 + 128 + n];   // V-half row, coalesced
    __syncthreads();
    float s0 = 0, s1 = 0, s2 = 0, s3 = 0;
#pragma unroll 8
    for (int m = 0; m < 128; m += 4) {   // Wp reads coalesced over n
      s0 += wv[kk][m]     * Wp[(m)     * 128 + n];
      s1 += wv[kk][m + 1] * Wp[(m + 1) * 128 + n];
      s2 += wv[kk][m + 2] * Wp[(m + 2) * 128 + n];
      s3 += wv[kk][m + 3] * Wp[(m + 3) * 128 + n];
    }
    WcT[n * 392 + (2 * b + kk)] = f2bf(s0 + s1 + s2 + s3);
  } else if (b == 192) {               // bc[n] = bp[n] + bkv[128:]@Wp[:,n]
    if (tid < 128) {
      float s = bp[tid];
#pragma unroll 8
      for (int m = 0; m < 128; ++m) s += bkv[128 + m] * Wp[m * 128 + tid];
      bc[tid] = s;
    }
  } else if (b < 449) {                // W1T[n*136+k] = W1[k*512+n]
    const int id = (b - 193) * 256 + tid;
    const int k = id >> 9, n = id & 511;
    W1T[n * 136 + k] = f2bf(W1[k * 512 + n]);
  } else {                             // W2T[ch][n][72]: W2[k*128+n], ch=k>>6
    const int id = (b - 449) * 256 + tid;
    const int k = id >> 7, n = id & 127;
    W2T[(k >> 6) * 9216 + n * 72 + (k & 63)] = f2bf(W2[k * 128 + n]);
  }
}

// ---------------- K1: LN1 + y-GEMM + LN2 -> yb, lb (bf16, frag-major) --------
// Frag-major band layout: elem(tile64, band4, t8, r4, q4, c16) at
//   (tile*4+band)*2048 + ((t*4+r)*4+q)*16 + c16   <->  (row=band*16+q*4+r, col=t*16+c16)
// 256 persistent blocks (1/CU by LDS), 4 tiles each; WcT staged once per block.
__global__ __launch_bounds__(256)
void k1(const float* __restrict__ x,  const float* __restrict__ g1,
        const float* __restrict__ b1, const float* __restrict__ g2,
        const float* __restrict__ b2,
        const short* __restrict__ WcTg, const float* __restrict__ bcg,
        short* __restrict__ yb, short* __restrict__ lb) {
  __shared__ __align__(16) short WcT_l[128 * 392];   // 100352 B
  __shared__ __align__(16) short A1[64 * 392];       // 50176 B (wave-private bands)
  __shared__ float bcf[128], g2f[128], b2f[128];
  const int tid = threadIdx.x, lane = tid & 63, w = tid >> 6;
  const int q = lane >> 4, c16 = lane & 15, arow = w * 16 + c16;

  {  // stage WcT (98 KB) once: 98 x 1KB wave-chunks
    const char* gsrc = (const char*)WcTg;
    for (int c = w; c < 98; c += 4)
      gload_lds16(gsrc + c * 1024 + lane * 16, (char*)WcT_l + c * 1024);
  }
  if (tid < 128) { bcf[tid] = bcg[tid]; g2f[tid] = g2[tid]; b2f[tid] = b2[tid]; }
  __syncthreads();  // full vmcnt/lgkm drain before MFMA reads

  for (int it = 0; it < 4; ++it) {
    const long tile = (long)blockIdx.x * 4 + it;
    const long tok0 = tile * 64;
    // ---- S1: LN1(x) -> A1 bf16 (4 threads/row; wave w writes rows 16w..16w+15)
    {
      const int row = tid >> 2, part = tid & 3;
      const float* xp = x + (tok0 + row) * 384 + part * 96;
      float4 xv[24]; float s = 0.f, sq = 0.f;
#pragma unroll
      for (int i = 0; i < 24; ++i) {
        float4 v = ((const float4*)xp)[i]; xv[i] = v;
        s += v.x + v.y + v.z + v.w;
        sq += v.x * v.x + v.y * v.y + v.z * v.z + v.w * v.w;
      }
      s += __shfl_xor(s, 1);  s += __shfl_xor(s, 2);
      sq += __shfl_xor(sq, 1); sq += __shfl_xor(sq, 2);
      const float mean = s * (1.f / 384.f);
      const float rs = rsqrtf(sq * (1.f / 384.f) - mean * mean + 1e-5f);
      const float4* g1p = (const float4*)(g1 + part * 96);
      const float4* b1p = (const float4*)(b1 + part * 96);
      short* dst = A1 + row * 392 + part * 96;
#pragma unroll
      for (int i = 0; i < 24; ++i) {
        float4 g = g1p[i], bb = b1p[i], v = xv[i]; short4 o;
        o.x = f2bf((v.x - mean) * rs * g.x + bb.x);
        o.y = f2bf((v.y - mean) * rs * g.y + bb.y);
        o.z = f2bf((v.z - mean) * rs * g.z + bb.z);
        o.w = f2bf((v.w - mean) * rs * g.w + bb.w);
        ((short4*)dst)[i] = o;
      }
    }
    __syncthreads();
    // ---- S2: y = A1 @ WcT + bc (B from LDS)
    f32x4 yacc[8];
#pragma unroll
    for (int t = 0; t < 8; ++t) yacc[t] = (f32x4){0.f, 0.f, 0.f, 0.f};
#pragma unroll
    for (int ks = 0; ks < 12; ++ks) {
      bf16x8 af = *(const bf16x8*)(A1 + arow * 392 + ks * 32 + q * 8);
#pragma unroll
      for (int t = 0; t < 8; ++t) {
        bf16x8 bf = *(const bf16x8*)(WcT_l + (t * 16 + c16) * 392 + ks * 32 + q * 8);
        yacc[t] = __builtin_amdgcn_mfma_f32_16x16x32_bf16(af, bf, yacc[t], 0, 0, 0);
      }
    }
    // ---- LN2 stats (rows distinguished by (q,r); reduce over 16 c16-lanes)
    float sm[4] = {0, 0, 0, 0}, sv[4] = {0, 0, 0, 0};
#pragma unroll
    for (int t = 0; t < 8; ++t) {
      const float bb = bcf[t * 16 + c16];
#pragma unroll
      for (int r = 0; r < 4; ++r) {
        yacc[t][r] += bb; const float v = yacc[t][r]; sm[r] += v; sv[r] += v * v;
      }
    }
#pragma unroll
    for (int r = 0; r < 4; ++r) {
      sm[r] += __shfl_xor(sm[r], 1); sm[r] += __shfl_xor(sm[r], 2);
      sm[r] += __shfl_xor(sm[r], 4); sm[r] += __shfl_xor(sm[r], 8);
      sv[r] += __shfl_xor(sv[r], 1); sv[r] += __shfl_xor(sv[r], 2);
      sv[r] += __shfl_xor(sv[r], 4); sv[r] += __shfl_xor(sv[r], 8);
    }
    // ---- store y & ln2y, frag-major (fully coalesced 128B/instr)
    short* ybp = yb + (tile * 4 + w) * 2048;
    short* lbp = lb + (tile * 4 + w) * 2048;
#pragma unroll
    for (int r = 0; r < 4; ++r) {
      const float mn = sm[r] * (1.f / 128.f);
      const float rv = rsqrtf(sv[r] * (1.f / 128.f) - mn * mn + 1e-5f);
#pragma unroll
      for (int t = 0; t < 8; ++t) {
        const int off = ((t * 4 + r) * 4 + q) * 16 + c16;
        const float yv = yacc[t][r];
        ybp[off] = f2bf(yv);
        lbp[off] = f2bf((yv - mn) * rv * g2f[t * 16 + c16] + b2f[t * 16 + c16]);
      }
    }
    // no end barrier: A1 bands are wave-private; in-wave LDS order suffices
  }
}

// ---------------- K2: MLP + residual. 512 blocks x 2 tiles; ch-chunked weights.
__global__ __launch_bounds__(256)
void k2(const short* __restrict__ yb, const short* __restrict__ lb,
        const short* __restrict__ W1Tg, const short* __restrict__ W2Tg,
        const float* __restrict__ bm1, const float* __restrict__ bm2,
        float* __restrict__ out) {
  __shared__ __align__(16) short W1c[64 * 136];    // 17408 B (17 x 1KB)
  __shared__ __align__(16) short W2c[128 * 72];    // 18432 B (18 x 1KB)
  __shared__ __align__(16) short A3s[4][16 * 72];  // wave-private gelu buf
  __shared__ float bm1f[512], bm2f[128];
  const int tid = threadIdx.x, lane = tid & 63, w = tid >> 6;
  const int q = lane >> 4, c16 = lane & 15;
  if (tid < 128) ((float4*)bm1f)[tid] = ((const float4*)bm1)[tid];
  else if (tid < 160) ((float4*)bm2f)[tid - 128] = ((const float4*)bm2)[tid - 128];

  const long tpair = blockIdx.x;   // tiles 2*tpair, 2*tpair+1
  // A2 frags (ln2y) for both tiles: coalesced b128 from frag-major layout
  bf16x8 a2[2][4];
#pragma unroll
  for (int u = 0; u < 2; ++u) {
    const short* base = lb + ((2 * tpair + u) * 4 + w) * 2048;
#pragma unroll
    for (int ks = 0; ks < 4; ++ks) {
      const int t = ks * 2 + (q >> 1);
      const int off = ((t * 4 + (c16 & 3)) * 4 + (c16 >> 2)) * 16 + (q & 1) * 8;
      a2[u][ks] = *(const bf16x8*)(base + off);
    }
  }
  f32x4 zacc[2][8];
#pragma unroll
  for (int u = 0; u < 2; ++u)
#pragma unroll
    for (int t = 0; t < 8; ++t) zacc[u][t] = (f32x4){0.f, 0.f, 0.f, 0.f};

  for (int ch = 0; ch < 8; ++ch) {
    const char* g1s = (const char*)W1Tg + ch * 17408;
    const char* g2s = (const char*)W2Tg + ch * 18432;
    for (int c = w; c < 17; c += 4) gload_lds16(g1s + c * 1024 + lane * 16, (char*)W1c + c * 1024);
    for (int c = w; c < 18; c += 4) gload_lds16(g2s + c * 1024 + lane * 16, (char*)W2c + c * 1024);
    __syncthreads();
#pragma unroll
    for (int u = 0; u < 2; ++u) {
      f32x4 hacc[4];
#pragma unroll
      for (int tt = 0; tt < 4; ++tt) hacc[tt] = (f32x4){0.f, 0.f, 0.f, 0.f};
#pragma unroll
      for (int ks = 0; ks < 4; ++ks)
#pragma unroll
        for (int tt = 0; tt < 4; ++tt) {
          bf16x8 bf = *(const bf16x8*)(W1c + (tt * 16 + c16) * 136 + ks * 32 + q * 8);
          hacc[tt] = __builtin_amdgcn_mfma_f32_16x16x32_bf16(a2[u][ks], bf, hacc[tt], 0, 0, 0);
        }
      short* a3 = A3s[w];
#pragma unroll
      for (int tt = 0; tt < 4; ++tt) {
        const float bb = bm1f[ch * 64 + tt * 16 + c16];
#pragma unroll
        for (int r = 0; r < 4; ++r) {
          const float h = hacc[tt][r] + bb;
          a3[(q * 4 + r) * 72 + tt * 16 + c16] =
              f2bf(0.5f * h * (1.f + erff(h * 0.70710678118f)));
        }
      }
      // in-wave cross-lane LDS dependence: force order + drain
      asm volatile("s_waitcnt lgkmcnt(0)" ::: "memory");
#pragma unroll
      for (int ks = 0; ks < 2; ++ks) {
        bf16x8 af = *(const bf16x8*)(a3 + c16 * 72 + ks * 32 + q * 8);
#pragma unroll
        for (int t = 0; t < 8; ++t) {
          bf16x8 bf = *(const bf16x8*)(W2c + (t * 16 + c16) * 72 + ks * 32 + q * 8);
          zacc[u][t] = __builtin_amdgcn_mfma_f32_16x16x32_bf16(af, bf, zacc[u][t], 0, 0, 0);
        }
      }
    }
    __syncthreads();   // all waves done with W1c/W2c before restage
  }
  // ---- epilogue: z = y + mlp + bm2 (y reads coalesced; out 64B segments)
#pragma unroll
  for (int u = 0; u < 2; ++u) {
    const long tile = 2 * tpair + u;
    const short* ybase = yb + (tile * 4 + w) * 2048;
#pragma unroll
    for (int t = 0; t < 8; ++t) {
      const float bb = bm2f[t * 16 + c16];
#pragma unroll
      for (int r = 0; r < 4; ++r) {
        const float yv = bf2f(ybase[((t * 4 + r) * 4 + q) * 16 + c16]);
        const long rowg = tile * 64 + w * 16 + q * 4 + r;
        out[rowg * 128 + t * 16 + c16] = yv + zacc[u][t][r] + bb;
      }
    }
  }
}

extern "C" void kernel_launch(void* const* d_in, const int* in_sizes, int n_in,
                              void* d_out, int out_size, void* d_ws, size_t ws_size,
                              hipStream_t stream) {
  const float* x   = (const float*)d_in[0];
  const float* g1  = (const float*)d_in[1];
  const float* b1  = (const float*)d_in[2];
  // d_in[3]=Wq, [4]=bq, [7]=rpb dead (softmax over size-1 axis == 1)
  const float* Wkv = (const float*)d_in[5];
  const float* bkv = (const float*)d_in[6];
  const float* Wp  = (const float*)d_in[8];
  const float* bp  = (const float*)d_in[9];
  const float* g2  = (const float*)d_in[10];
  const float* b2  = (const float*)d_in[11];
  const float* W1  = (const float*)d_in[12];
  const float* bm1 = (const float*)d_in[13];
  const float* W2  = (const float*)d_in[14];
  const float* bm2 = (const float*)d_in[15];

  char* ws = (char*)d_ws;
  short* WcT = (short*)(ws + 0);          // 100,352 B
  short* W1T = (short*)(ws + 100352);     // 139,264 B
  short* W2T = (short*)(ws + 239616);     // 147,456 B
  float* bc  = (float*)(ws + 387072);     // 512 B
  short* yb  = (short*)(ws + 387584);     // 16,777,216 B
  short* lb  = (short*)(ws + 17164800);   // 16,777,216 B  (total ~32.4 MiB)

  prep<<<705, 256, 0, stream>>>(Wkv, bkv, Wp, bp, W1, W2, WcT, W1T, W2T, bc);
  k1<<<256, 256, 0, stream>>>(x, g1, b1, g2, b2, WcT, bc, yb, lb);
  k2<<<512, 256, 0, stream>>>(yb, lb, W1T, W2T, bm1, bm2, (float*)d_out);
}